// Round 13
// baseline (518.352 us; speedup 1.0000x reference)
//
#include <hip/hip_runtime.h>
#include <hip/hip_cooperative_groups.h>
#include <cstdint>
#include <cstdlib>
#include <cstring>
#include <vector>

namespace cg = cooperative_groups;

#define RW_VOCAB 512
#define RW_T 64
#define RW_NIN 2048
#define RW_NBIAS 2
#define RW_BATCH 512
#define RW_NLAYERS 6
#define RW_VBLD 4096
#define NBLK 256

typedef __attribute__((ext_vector_type(8))) short short8;  // bf16x8 frag
typedef __attribute__((ext_vector_type(4))) float f32x4;
typedef uint32_t u32;

// ---------------------------------------------------------------------------
// Host-side replication of np.random.RandomState(0) graph construction.
// (verified passing: rounds 3, 5, 6, 10, 12; absmax <= 9.8e-4.)
// ---------------------------------------------------------------------------
namespace {

struct MT19937 {
  uint32_t mt[624];
  int mti;
  void seed(uint32_t s) {
    for (int i = 0; i < 624; ++i) {
      mt[i] = s;
      s = 1812433253u * (s ^ (s >> 30)) + (uint32_t)i + 1u;
    }
    mti = 624;
  }
  inline uint32_t next() {
    if (mti >= 624) {
      for (int i = 0; i < 624; ++i) {
        uint32_t y = (mt[i] & 0x80000000u) | (mt[(i + 1) % 624] & 0x7fffffffu);
        mt[i] = mt[(i + 397) % 624] ^ (y >> 1) ^ ((y & 1u) ? 2567483615u : 0u);
      }
      mti = 0;
    }
    uint32_t y = mt[mti++];
    y ^= y >> 11;
    y ^= (y << 7) & 2636928640u;
    y ^= (y << 15) & 4022730752u;
    y ^= y >> 18;
    return y;
  }
  inline double rnd() {
    uint32_t a = next() >> 5, b = next() >> 6;
    return ((double)a * 67108864.0 + (double)b) / 9007199254740992.0;
  }
};

const int LAYER_SIZES[RW_NLAYERS] = {288, 288, 288, 287, 287, 512};
const int LAYER_START[RW_NLAYERS] = {2050, 2338, 2626, 2914, 3201, 3488};
const int LAYER_NPAD[RW_NLAYERS] = {288, 288, 288, 288, 288, 512};
const int LAYER_NT[RW_NLAYERS] = {9, 9, 9, 9, 9, 16};
const int LAYER_SK[RW_NLAYERS] = {7, 7, 7, 7, 7, 4};

struct FArgsH {
  int p0[RW_NLAYERS], ep[RW_NLAYERS], er[RW_NLAYERS], w0[RW_NLAYERS];
  int kpad[RW_NLAYERS], ck[RW_NLAYERS], sk[RW_NLAYERS], nt[RW_NLAYERS];
  int nsize[RW_NLAYERS], vstart[RW_NLAYERS];
  unsigned wofs[RW_NLAYERS];
  int Epad, nwdt4;
};

struct HostGraph {
  FArgsH fa;
  unsigned wdt_elems;
  uint32_t* h_pack;  // pinned: (dst_local<<12)|src_global
};

HostGraph* build_host_graph() {
  auto* G = new HostGraph();
  MT19937 mt;
  mt.seed(0);
  std::vector<uint32_t> pack;
  pack.reserve(180000);
  int start = RW_NIN + RW_NBIAS;  // 2050
  int wcum = 0;
  for (int li = 0; li < RW_NLAYERS; ++li) {
    const int size = LAYER_SIZES[li];
    G->fa.p0[li] = (int)pack.size();
    G->fa.w0[li] = wcum;
    int cnt = 0;
    for (int u = 0; u < start; ++u) {  // src-major == numpy nonzero order
      for (int v = 0; v < size; ++v) {
        if (mt.rnd() < 0.03) {
          pack.push_back(((uint32_t)v << 12) | (uint32_t)u);
          ++cnt;
        }
      }
    }
    G->fa.er[li] = cnt;
    wcum += cnt;
    while (pack.size() & 3u) pack.push_back(0u);
    G->fa.ep[li] = (int)pack.size() - G->fa.p0[li];
    start += size;
  }
  G->fa.Epad = (int)pack.size();
  unsigned ofs = 0;
  for (int li = 0; li < RW_NLAYERS; ++li) {
    G->fa.kpad[li] = ((LAYER_START[li] + 63) / 64) * 64;
    G->fa.wofs[li] = ofs;
    ofs += (unsigned)LAYER_NPAD[li] * (unsigned)G->fa.kpad[li];
    G->fa.sk[li] = LAYER_SK[li];
    G->fa.nt[li] = LAYER_NT[li];
    G->fa.nsize[li] = LAYER_SIZES[li];
    G->fa.vstart[li] = LAYER_START[li];
    G->fa.ck[li] = ((G->fa.kpad[li] + LAYER_SK[li] - 1) / LAYER_SK[li] + 63) &
                   ~63;
  }
  G->wdt_elems = ofs;
  G->fa.nwdt4 = (int)(ofs / 8);
  const size_t bytes = (size_t)G->fa.Epad * 4;
  if (hipHostMalloc((void**)&G->h_pack, bytes) != hipSuccess)
    G->h_pack = (uint32_t*)malloc(bytes);
  memcpy(G->h_pack, pack.data(), bytes);
  return G;
}

}  // namespace

struct FArgs {
  int p0[RW_NLAYERS], ep[RW_NLAYERS], er[RW_NLAYERS], w0[RW_NLAYERS];
  int kpad[RW_NLAYERS], ck[RW_NLAYERS], sk[RW_NLAYERS], nt[RW_NLAYERS];
  int nsize[RW_NLAYERS], vstart[RW_NLAYERS];
  unsigned wofs[RW_NLAYERS];
  int Epad, nwdt4;
};

__device__ __forceinline__ unsigned short f2bf(float f) {
  unsigned u = __builtin_bit_cast(unsigned, f);
  return (unsigned short)((u + 0x7fffu + ((u >> 16) & 1u)) >> 16);  // RNE
}

// ---------------------------------------------------------------------------
// Fused cooperative kernel: init -> scatter -> 6x (GEMM -> epi), with
// grid.sync() between phases. Phase internals identical to the R12-measured
// kernels (reg-prefetch BK=64 GEMM, fp32-atomic pre, tiny epilogue).
// ---------------------------------------------------------------------------
__global__ __launch_bounds__(256) void rwnn_fused(
    const uint32_t* __restrict__ pack, const float* __restrict__ w,
    unsigned short* __restrict__ wdt, unsigned short* __restrict__ vb,
    float* __restrict__ pre, const int* __restrict__ ids,
    const float* __restrict__ tok, const float* __restrict__ pos,
    float* __restrict__ out, FArgs ga) {
  cg::grid_group grid = cg::this_grid();
  __shared__ unsigned short As[128 * 64];  // 16 KB, row stride 128 B
  __shared__ unsigned short Bs[32 * 64];   // 4 KB
  const int tid = threadIdx.x;
  const int bid = blockIdx.x;
  const int gt = bid * 256 + tid;
  const int gs = NBLK * 256;

  // ---- phase 0: init (zero W^T, zero pre, build Vb) ----
  {
    const uint4 z = {0u, 0u, 0u, 0u};
    uint4* wdt4 = (uint4*)wdt;
    for (int i = gt; i < ga.nwdt4; i += gs) wdt4[i] = z;
    uint4* pre4 = (uint4*)pre;
    for (int i = gt; i < RW_BATCH * 512 / 4; i += gs) pre4[i] = z;
    uint4* vb4 = (uint4*)vb;
    for (int i = gt; i < RW_BATCH * (RW_VBLD / 8); i += gs) {
      const int b = i >> 9, j = i & 511;
      const int c0 = j * 8;
      uint4 val = z;
      if (c0 + 8 <= RW_NIN) {
        const int id = ids[b * RW_T + (c0 >> 5)];
        const float4 t0 = *(const float4*)(tok + id * 32 + (c0 & 31));
        const float4 t1 = *(const float4*)(tok + id * 32 + (c0 & 31) + 4);
        const float4 p0 = *(const float4*)(pos + c0);
        const float4 p1 = *(const float4*)(pos + c0 + 4);
        val.x = (u32)f2bf(t0.x + p0.x) | ((u32)f2bf(t0.y + p0.y) << 16);
        val.y = (u32)f2bf(t0.z + p0.z) | ((u32)f2bf(t0.w + p0.w) << 16);
        val.z = (u32)f2bf(t1.x + p1.x) | ((u32)f2bf(t1.y + p1.y) << 16);
        val.w = (u32)f2bf(t1.z + p1.z) | ((u32)f2bf(t1.w + p1.w) << 16);
      } else if (c0 == RW_NIN) {
        val.x = 0x3f803f80u;  // two bias nodes = bf16 1.0
      }
      vb4[(size_t)b * (RW_VBLD / 8) + j] = val;
    }
  }
  grid.sync();

  // ---- phase 1: scatter sparse weights into dense bf16 W^T ----
  for (int i = gt; i < ga.Epad; i += gs) {
    int l = 0;
#pragma unroll
    for (int k = 1; k < RW_NLAYERS; ++k)
      if (i >= ga.p0[k]) l = k;
    const int kk = i - ga.p0[l];
    if (kk < ga.er[l]) {
      const uint32_t pk = pack[i];
      const unsigned u = pk & 4095u, v = pk >> 12;
      wdt[ga.wofs[l] + (size_t)v * (unsigned)ga.kpad[l] + u] =
          f2bf(w[ga.w0[l] + kk]);
    }
  }
  grid.sync();

  // ---- layers ----
  const int wave = tid >> 6, lane = tid & 63;
  const int lr = lane & 15, gc4 = lane >> 4, lq = lane >> 4;
  const int arow = tid >> 3;                 // 0..31
  const int ach = tid & 7;                   // 16B chunk 0..7
  const int aswz = (ach ^ (arow & 7)) << 4;  // swizzled byte offset in row

  for (int l = 0; l < RW_NLAYERS; ++l) {
    const int SK = ga.sk[l], NT = ga.nt[l];
    const int kpad = ga.kpad[l], ck = ga.ck[l];
    const int mt = bid & 3;
    const int rest = bid >> 2;
    const int nt_ = rest % NT;
    const int sk_ = rest / NT;

    if (sk_ < SK) {  // this block owns a (mt, nt_, sk_) tile
      const unsigned short* Bt = wdt + ga.wofs[l];
      const int k0 = sk_ * ck;
      const int k1 = min(k0 + ck, kpad);
      const int nit = (k1 - k0 + 63) >> 6;  // >=1 for all configured tiles

      const unsigned short* gA =
          vb + (size_t)(mt * 128 + arow) * RW_VBLD + ach * 8;
      const unsigned short* gB =
          Bt + (size_t)(nt_ * 32 + arow) * kpad + ach * 8;
      float4 pfa0, pfa1, pfa2, pfa3, pfb;

#define LOADREGS(kk)                                                  \
  do {                                                                \
    pfa0 = *(const float4*)(gA + (kk));                               \
    pfa1 = *(const float4*)(gA + (size_t)32 * RW_VBLD + (kk));        \
    pfa2 = *(const float4*)(gA + (size_t)64 * RW_VBLD + (kk));        \
    pfa3 = *(const float4*)(gA + (size_t)96 * RW_VBLD + (kk));        \
    pfb = *(const float4*)(gB + (kk));                                \
  } while (0)

      LOADREGS(k0);
      f32x4 acc[2][2] = {};

      for (int t = 0; t < nit; ++t) {
        __syncthreads();  // previous tile's compute done; LDS reusable
        *(float4*)((char*)As + (arow)*128 + aswz) = pfa0;
        *(float4*)((char*)As + (32 + arow) * 128 + aswz) = pfa1;
        *(float4*)((char*)As + (64 + arow) * 128 + aswz) = pfa2;
        *(float4*)((char*)As + (96 + arow) * 128 + aswz) = pfa3;
        *(float4*)((char*)Bs + arow * 128 + aswz) = pfb;
        __syncthreads();  // tile ready
        if (t + 1 < nit) LOADREGS(k0 + (t + 1) * 64);  // prefetch
#pragma unroll
        for (int kk = 0; kk < 2; ++kk) {
          const int sa = ((kk * 4 + gc4) ^ (lr & 7)) << 4;
          const short8 a0 =
              *(const short8*)((char*)As + (wave * 32 + lr) * 128 + sa);
          const short8 a1 =
              *(const short8*)((char*)As + (wave * 32 + 16 + lr) * 128 + sa);
          const short8 b0 = *(const short8*)((char*)Bs + lr * 128 + sa);
          const short8 b1 = *(const short8*)((char*)Bs + (16 + lr) * 128 + sa);
          acc[0][0] = __builtin_amdgcn_mfma_f32_16x16x32_bf16(a0, b0,
                                                              acc[0][0], 0, 0, 0);
          acc[0][1] = __builtin_amdgcn_mfma_f32_16x16x32_bf16(a0, b1,
                                                              acc[0][1], 0, 0, 0);
          acc[1][0] = __builtin_amdgcn_mfma_f32_16x16x32_bf16(a1, b0,
                                                              acc[1][0], 0, 0, 0);
          acc[1][1] = __builtin_amdgcn_mfma_f32_16x16x32_bf16(a1, b1,
                                                              acc[1][1], 0, 0, 0);
        }
      }
#undef LOADREGS

#pragma unroll
      for (int ms = 0; ms < 2; ++ms)
#pragma unroll
        for (int ns = 0; ns < 2; ++ns)
#pragma unroll
          for (int r = 0; r < 4; ++r) {
            const int grow = mt * 128 + wave * 32 + ms * 16 + lq * 4 + r;
            const int gcol = nt_ * 32 + ns * 16 + lr;
            atomicAdd(pre + (size_t)grow * 512 + gcol, acc[ms][ns][r]);
          }
    }
    grid.sync();  // all tile contributions landed in pre

    // ---- epilogue: rows 2*bid, 2*bid+1 ----
    {
      const int nsize = ga.nsize[l], vstart = ga.vstart[l];
      const int last = (l == RW_NLAYERS - 1);
#pragma unroll
      for (int rr = 0; rr < 2; ++rr) {
        const int b = bid * 2 + rr;
        for (int n = tid; n < 512; n += 256) {
          const float v = pre[(size_t)b * 512 + n];
          pre[(size_t)b * 512 + n] = 0.0f;
          if (n < nsize) {
            if (last)
              out[(size_t)b * 512 + n] = v;
            else
              vb[(size_t)b * RW_VBLD + vstart + n] = f2bf(tanhf(v));
          }
        }
      }
    }
    if (l + 1 < RW_NLAYERS) grid.sync();  // vb ready + pre re-zeroed
  }
}

// ---------------------------------------------------------------------------
// Fallback (verified round-5 path) if ws_size too small for the dense plan
// ---------------------------------------------------------------------------
__global__ __launch_bounds__(256) void rwnn_build_w(const float* __restrict__ w,
                                                    float* __restrict__ wpad,
                                                    FArgs ga, int Epad) {
  const int i = blockIdx.x * 256 + threadIdx.x;
  if (i >= Epad) return;
  int l = 0;
#pragma unroll
  for (int k = 1; k < RW_NLAYERS; ++k)
    if (i >= ga.p0[k]) l = k;
  const int kk = i - ga.p0[l];
  wpad[i] = (kk < ga.er[l]) ? w[ga.w0[l] + kk] : 0.0f;
}

__global__ __launch_bounds__(512) void rwnn_fwd_sparse(
    const int* __restrict__ ids, const float* __restrict__ tok,
    const float* __restrict__ pos, const uint32_t* __restrict__ pack,
    const float* __restrict__ wpad, float* __restrict__ out, FArgs ga) {
  __shared__ float vals[4000];
  const int b = blockIdx.x;
  const int tid = threadIdx.x;
  for (int i = tid; i < RW_NIN; i += 512) {
    const int t = i >> 5, d = i & 31;
    vals[i] = tok[(ids[b * RW_T + t] << 5) + d] + pos[i];
  }
  if (tid < RW_NBIAS) vals[RW_NIN + tid] = 1.0f;
  const int sizes[RW_NLAYERS] = {288, 288, 288, 287, 287, 512};
  int nb = RW_NIN + RW_NBIAS;
  for (int li = 0; li < RW_NLAYERS; ++li) {
    const int size = sizes[li];
    __syncthreads();
    for (int v = tid; v < size; v += 512) vals[nb + v] = 0.0f;
    __syncthreads();
    const int p0 = ga.p0[li], ng = ga.ep[li] >> 2;
    for (int g = tid; g < ng; g += 512) {
      const int e = p0 + (g << 2);
      const uint4 pk = *reinterpret_cast<const uint4*>(pack + e);
      const float4 wv = *reinterpret_cast<const float4*>(wpad + e);
      atomicAdd(&vals[nb + (pk.x >> 12)], vals[pk.x & 4095u] * wv.x);
      atomicAdd(&vals[nb + (pk.y >> 12)], vals[pk.y & 4095u] * wv.y);
      atomicAdd(&vals[nb + (pk.z >> 12)], vals[pk.z & 4095u] * wv.z);
      atomicAdd(&vals[nb + (pk.w >> 12)], vals[pk.w & 4095u] * wv.w);
    }
    __syncthreads();
    if (li == RW_NLAYERS - 1) {
      for (int v = tid; v < RW_VOCAB; v += 512)
        out[b * RW_VOCAB + v] = vals[nb + v];
    } else {
      for (int v = tid; v < size; v += 512) vals[nb + v] = tanhf(vals[nb + v]);
    }
    nb += size;
  }
}

// ---------------------------------------------------------------------------
extern "C" void kernel_launch(void* const* d_in, const int* in_sizes, int n_in,
                              void* d_out, int out_size, void* d_ws,
                              size_t ws_size, hipStream_t stream) {
  static HostGraph* G = build_host_graph();
  const int Epad = G->fa.Epad;

  const int* ids = (const int*)d_in[0];
  const float* tok = (const float*)d_in[1];
  const float* pos = (const float*)d_in[2];
  const float* w = (const float*)d_in[3];
  float* out = (float*)d_out;

  FArgs ga;
  memcpy(&ga, &G->fa, sizeof(FArgs));

  char* ws = (char*)d_ws;
  const size_t packB = ((size_t)Epad * 4 + 255) & ~(size_t)255;
  const size_t wdtB = ((size_t)G->wdt_elems * 2 + 255) & ~(size_t)255;
  const size_t vbB = (size_t)RW_BATCH * RW_VBLD * 2;  // 4 MB
  const size_t preB = (size_t)RW_BATCH * 512 * 4;     // 1 MB
  const size_t need = packB + wdtB + vbB + preB;

  uint32_t* d_pack = (uint32_t*)ws;
  hipMemcpyAsync(d_pack, G->h_pack, (size_t)Epad * 4, hipMemcpyHostToDevice,
                 stream);

  if (ws_size < need) {  // fallback: verified sparse path
    float* d_wpad = (float*)(ws + packB);
    rwnn_build_w<<<(Epad + 255) / 256, 256, 0, stream>>>(w, d_wpad, ga, Epad);
    rwnn_fwd_sparse<<<RW_BATCH, 512, 0, stream>>>(ids, tok, pos, d_pack,
                                                  d_wpad, out, ga);
    return;
  }

  unsigned short* d_wdt = (unsigned short*)(ws + packB);
  unsigned short* d_vb = (unsigned short*)(ws + packB + wdtB);
  float* d_pre = (float*)(ws + packB + wdtB + vbB);

  void* kargs[] = {(void*)&d_pack, (void*)&w,   (void*)&d_wdt,
                   (void*)&d_vb,   (void*)&d_pre, (void*)&ids,
                   (void*)&tok,    (void*)&pos, (void*)&out, (void*)&ga};
  hipLaunchCooperativeKernel((const void*)rwnn_fused, dim3(NBLK), dim3(256),
                             kargs, 0, stream);
}